// Round 12
// baseline (52.428 us; speedup 1.0000x reference)
//
#include <hip/hip_runtime.h>
#include <math.h>

#define C 32
#define OUT_DIM 288
#define MAXDEG 64
#define AGG_ROWS 17
#define AGG_S (AGG_ROWS * 32)   // 544 ushorts per node, node-major (bf16)
// agg rows: 0:a0a 1:a0b 2-4:a1a 5-7:a1b 8-12:a2 13:x0 14-16:x1

typedef __attribute__((ext_vector_type(8))) short short8v;   // 8 bf16 (4 VGPRs)
typedef __attribute__((ext_vector_type(4))) float float4v;   // MFMA accumulator

__device__ __forceinline__ float4v mfma_bf16(short8v a, short8v b, float4v c) {
    return __builtin_amdgcn_mfma_f32_16x16x32_bf16(a, b, c, 0, 0, 0);
}

// f32 -> bf16 bits, round-to-nearest-even
__device__ __forceinline__ unsigned short f2b(float x) {
    unsigned int u = __float_as_uint(x);
    u = u + 0x7FFFu + ((u >> 16) & 1u);
    return (unsigned short)(u >> 16);
}

__device__ __forceinline__ float gelu_tanh(float x) {
    // jax.nn.gelu approximate=True
    float x3 = x * x * x;
    float t = tanhf(0.7978845608028654f * (x + 0.044715f * x3));
    return 0.5f * x * (1.0f + t);
}

__global__ void zero_kernel(int* __restrict__ p, int n) {
    int i = blockIdx.x * 256 + threadIdx.x;
    if (i < n) p[i] = 0;
}

// Transpose+convert the 8 weight matrices to bf16: wt block b holds WT[d][c].
// blocks: 0:pre0_lo 1:pre0_hi 2:pre1_lo 3:pre1_hi 4:pre2 5:post0 6:post1
//         7:post2 8:sc0 9:sc1
__global__ void wprep_kernel(const float* __restrict__ Wpre0,
                             const float* __restrict__ Wpre1,
                             const float* __restrict__ Wpre2,
                             const float* __restrict__ Wpost0,
                             const float* __restrict__ Wpost1,
                             const float* __restrict__ Wpost2,
                             const float* __restrict__ Wsc0,
                             const float* __restrict__ Wsc1,
                             unsigned short* __restrict__ wt) {
    const int b = blockIdx.x;
    const float* src;
    switch (b) {
        case 0: src = Wpre0;        break;
        case 1: src = Wpre0 + 1024; break;
        case 2: src = Wpre1;        break;
        case 3: src = Wpre1 + 1024; break;
        case 4: src = Wpre2;        break;
        case 5: src = Wpost0;       break;
        case 6: src = Wpost1;       break;
        case 7: src = Wpost2;       break;
        case 8: src = Wsc0;         break;
        default: src = Wsc1;        break;
    }
    unsigned short* dst = wt + b * 1024;
    for (int i = threadIdx.x; i < 1024; i += 256) {
        const int cc = i >> 5, dd = i & 31;
        dst[dd * 32 + cc] = f2b(src[cc * 32 + dd]);
    }
}

// Scatter into fixed-stride bins + spherical-harmonic precompute.
__global__ void scatter_sh_kernel(const int* __restrict__ recv,
                                  const int* __restrict__ senders,
                                  const float* __restrict__ pos, int E,
                                  int* __restrict__ counts, float4* __restrict__ adj) {
    int e = blockIdx.x * 256 + threadIdx.x;
    if (e < E) {
        const int r = recv[e];
        const int s = senders[e];
        const float rx = pos[r * 3 + 0] - pos[s * 3 + 0];
        const float ry = pos[r * 3 + 1] - pos[s * 3 + 1];
        const float rz = pos[r * 3 + 2] - pos[s * 3 + 2];
        const float nrm = sqrtf(rx * rx + ry * ry + rz * rz);
        const float f = 1.7320508075688772f / fmaxf(nrm, 1e-9f);  // sqrt(3)/|r|
        const int p = atomicAdd(&counts[r], 1);
        if (p < MAXDEG)
            adj[(size_t)r * MAXDEG + p] = make_float4(rx * f, ry * f, rz * f, __int_as_float(s));
    }
}

// K1: 2 waves per node (portion split) x half split -> 8 gather chains/node.
// Raw (unscaled) partial sums combined through LDS; scaling + f2b at write.
__global__ __launch_bounds__(256) void edge_agg_kernel(
    const float* __restrict__ node0, const float* __restrict__ node1,
    const int* __restrict__ counts, const float4* __restrict__ adj,
    unsigned short* __restrict__ aggb, int N)
{
    __shared__ float prt[2][2][13][32];  // [slot][portion][row][c]

    const int tid     = threadIdx.x;
    const int wv      = tid >> 6;
    const int slot    = wv >> 1;
    const int portion = wv & 1;
    const int lane    = tid & 63;
    const int half    = lane >> 5;
    const int c       = lane & 31;
    const int node    = blockIdx.x * 2 + slot;
    const bool valid  = (node < N);

    const float S2 = 0.70710678118654752f;   // 1/sqrt(2)
    const float S6 = 0.40824829046386302f;   // 1/sqrt(6)
    const float INV_SQRT3 = 0.57735026918962576f;
    const float INV_DEN = 1.0f / 16.0f;

    float ax0 = 0.f, atp0 = 0.f;
    float ax1x = 0.f, ax1y = 0.f, ax1z = 0.f;
    float at1x = 0.f, at1y = 0.f, at1z = 0.f;
    float a2v0 = 0.f, a2v1 = 0.f, a2v2 = 0.f, a2v3 = 0.f, a2v4 = 0.f;

#define EDGE_ACC(A, X0, U1)                                                 \
    {                                                                       \
        const float shx = (A).x, shy = (A).y, shz = (A).z;                  \
        ax0 += (X0);                                                        \
        atp0 += (U1).x * shx + (U1).y * shy + (U1).z * shz;                 \
        ax1x += (U1).x; ax1y += (U1).y; ax1z += (U1).z;                     \
        at1x += (X0) * shx; at1y += (X0) * shy; at1z += (X0) * shz;         \
        a2v0 += (U1).x * shy + (U1).y * shx;                                \
        a2v1 += (U1).y * shz + (U1).z * shy;                                \
        a2v2 += 2.f * (U1).z * shz - (U1).x * shx - (U1).y * shy;           \
        a2v3 += (U1).x * shz + (U1).z * shx;                                \
        a2v4 += (U1).x * shx - (U1).y * shy;                                \
    }

    if (valid) {
        const int deg = min(counts[node], MAXDEG);
        const int beg = node * MAXDEG;
        const int end = beg + deg;
        int k = beg + portion * 2 + half;   // residues 0..3 mod 4
        while (k + 4 < end) {
            const float4 A0 = adj[k];
            const float4 A1 = adj[k + 4];
            const int b0 = __float_as_int(A0.w) * C + c;
            const int b1 = __float_as_int(A1.w) * C + c;
            const float q0 = node0[b0];
            const float q1 = node0[b1];
            const float3 u0 = *(const float3*)(node1 + b0 * 3);
            const float3 u1 = *(const float3*)(node1 + b1 * 3);
            EDGE_ACC(A0, q0, u0);
            EDGE_ACC(A1, q1, u1);
            k += 8;
        }
        if (k < end) {
            const float4 A0 = adj[k];
            const int b0 = __float_as_int(A0.w) * C + c;
            const float q0 = node0[b0];
            const float3 u0 = *(const float3*)(node1 + b0 * 3);
            EDGE_ACC(A0, q0, u0);
        }
    }
#undef EDGE_ACC

    // combine halves (totals land in both halves)
    ax0  += __shfl_xor(ax0, 32, 64);
    atp0 += __shfl_xor(atp0, 32, 64);
    ax1x += __shfl_xor(ax1x, 32, 64);
    ax1y += __shfl_xor(ax1y, 32, 64);
    ax1z += __shfl_xor(ax1z, 32, 64);
    at1x += __shfl_xor(at1x, 32, 64);
    at1y += __shfl_xor(at1y, 32, 64);
    at1z += __shfl_xor(at1z, 32, 64);
    a2v0 += __shfl_xor(a2v0, 32, 64);
    a2v1 += __shfl_xor(a2v1, 32, 64);
    a2v2 += __shfl_xor(a2v2, 32, 64);
    a2v3 += __shfl_xor(a2v3, 32, 64);
    a2v4 += __shfl_xor(a2v4, 32, 64);

    if (half == 0) {
        float* p = &prt[slot][portion][0][c];
        p[0 * 32]  = ax0;
        p[1 * 32]  = atp0;
        p[2 * 32]  = ax1x;
        p[3 * 32]  = ax1y;
        p[4 * 32]  = ax1z;
        p[5 * 32]  = at1x;
        p[6 * 32]  = at1y;
        p[7 * 32]  = at1z;
        p[8 * 32]  = a2v0;
        p[9 * 32]  = a2v1;
        p[10 * 32] = a2v2;
        p[11 * 32] = a2v3;
        p[12 * 32] = a2v4;
    }
    __syncthreads();

    if (valid) {
        unsigned short* ag = aggb + (size_t)node * AGG_S + c;
        const float SA = INV_DEN;
        const float SB = INV_DEN * INV_SQRT3;
        const float S2D = S2 * INV_DEN;
        const float S6D = S6 * INV_DEN;
#define PRT(j) (prt[slot][0][j][c] + prt[slot][1][j][c])
        if (portion == 0) {
            if (half == 0) {
                ag[0 * 32] = f2b(PRT(0) * SA);
                ag[1 * 32] = f2b(PRT(1) * SB);
                ag[2 * 32] = f2b(PRT(2) * SA);
                ag[3 * 32] = f2b(PRT(3) * SA);
                ag[4 * 32] = f2b(PRT(4) * SA);
                ag[5 * 32] = f2b(PRT(5) * SA);
                ag[6 * 32] = f2b(PRT(6) * SA);
            } else {
                ag[7 * 32]  = f2b(PRT(7) * SA);
                ag[8 * 32]  = f2b(PRT(8) * S2D);
                ag[9 * 32]  = f2b(PRT(9) * S2D);
                ag[10 * 32] = f2b(PRT(10) * S6D);
                ag[11 * 32] = f2b(PRT(11) * S2D);
                ag[12 * 32] = f2b(PRT(12) * S2D);
            }
        } else {
            if (half == 0) {
                const float x0n = node0[node * C + c];
                const float x1x = node1[(node * C + c) * 3 + 0];
                ag[13 * 32] = f2b(x0n);
                ag[14 * 32] = f2b(x1x);
            } else {
                const float x1y = node1[(node * C + c) * 3 + 1];
                const float x1z = node1[(node * C + c) * 3 + 2];
                ag[15 * 32] = f2b(x1y);
                ag[16 * 32] = f2b(x1z);
            }
        }
#undef PRT
    }
}

// K2: fused node update via MFMA. One wave = one (16-node tile, task t).
// B fragments are direct short8v loads from pre-transposed bf16 WT.
// Layouts (16x16x32 bf16): A: row=lane&15, k=(lane>>4)*8+j; B: col=lane&15,
// k=(lane>>4)*8+j; C/D: col=lane&15, row=(lane>>4)*4+reg [HW-verified R11].
__global__ __launch_bounds__(256) void node_mfma_kernel(
    const unsigned short* __restrict__ aggb,
    const unsigned short* __restrict__ wt,
    float* __restrict__ out, int N, int ntiles)
{
    __shared__ unsigned short tr[4][16][48];   // per-wave transpose slab

    const int wv   = threadIdx.x >> 6;
    const int wave = blockIdx.x * 4 + wv;
    const int tile = __builtin_amdgcn_readfirstlane(wave / 9);
    const int t    = __builtin_amdgcn_readfirstlane(wave % 9);
    if (tile >= ntiles) return;

    const int lane = threadIdx.x & 63;
    const int r    = lane & 15;
    const int kg   = lane >> 4;
    const int k0   = kg * 8;

    // task-dependent selections (wave-uniform)
    const unsigned short *pb1, *pb2 = nullptr, *qb1, *qb2 = nullptr;
    int rowA1, rowA2 = -1, rowX = -1, obase, ostride;
    if (t == 0) {
        rowA1 = 0; rowA2 = 1; rowX = 13;
        pb1 = wt + 0 * 1024; pb2 = wt + 1 * 1024;
        qb1 = wt + 5 * 1024; qb2 = wt + 8 * 1024;
        obase = 0; ostride = 1;
    } else if (t <= 3) {
        const int i = t - 1;
        rowA1 = 2 + i; rowA2 = 5 + i; rowX = 14 + i;
        pb1 = wt + 2 * 1024; pb2 = wt + 3 * 1024;
        qb1 = wt + 6 * 1024; qb2 = wt + 9 * 1024;
        obase = 32 + i; ostride = 3;
    } else {
        const int m = t - 4;
        rowA1 = 8 + m;
        pb1 = wt + 4 * 1024; qb1 = wt + 7 * 1024;
        obase = 128 + m; ostride = 5;
    }

    // ---- B fragments: contiguous 16B loads (WT[d][c], d = dt*16+r) ----
    short8v bp1[2], bp2[2], bq1[2], bq2[2];
#pragma unroll
    for (int dt = 0; dt < 2; ++dt) {
        const int d = dt * 16 + r;
        bp1[dt] = *(const short8v*)(pb1 + d * 32 + k0);
        bq1[dt] = *(const short8v*)(qb1 + d * 32 + k0);
    }
    if (rowA2 >= 0) {
#pragma unroll
        for (int dt = 0; dt < 2; ++dt) {
            const int d = dt * 16 + r;
            bp2[dt] = *(const short8v*)(pb2 + d * 32 + k0);
            bq2[dt] = *(const short8v*)(qb2 + d * 32 + k0);
        }
    }

    const int node = tile * 16 + r;
    const int nclamp = node < N ? node : (N - 1);
    const unsigned short* ap = aggb + (size_t)nclamp * AGG_S;

    // ---- pre-GEMM ----
    float4v acc0 = {0.f, 0.f, 0.f, 0.f};
    float4v acc1 = {0.f, 0.f, 0.f, 0.f};
    {
        const short8v a1 = *(const short8v*)(ap + rowA1 * 32 + k0);
        acc0 = mfma_bf16(a1, bp1[0], acc0);
        acc1 = mfma_bf16(a1, bp1[1], acc1);
    }
    if (rowA2 >= 0) {
        const short8v a2 = *(const short8v*)(ap + rowA2 * 32 + k0);
        acc0 = mfma_bf16(a2, bp2[0], acc0);
        acc1 = mfma_bf16(a2, bp2[1], acc1);
    }
    if (t == 0) {
#pragma unroll
        for (int q = 0; q < 4; ++q) {
            acc0[q] = gelu_tanh(acc0[q]);
            acc1[q] = gelu_tanh(acc1[q]);
        }
    }

    // ---- in-wave transpose: C layout -> A layout ----
#pragma unroll
    for (int q = 0; q < 4; ++q) {
        tr[wv][kg * 4 + q][r]      = f2b(acc0[q]);
        tr[wv][kg * 4 + q][16 + r] = f2b(acc1[q]);
    }
    asm volatile("s_waitcnt lgkmcnt(0)" ::: "memory");
    __builtin_amdgcn_sched_barrier(0);

    // ---- post-GEMM ----
    const short8v ha = *(const short8v*)&tr[wv][r][k0];
    float4v o0 = {0.f, 0.f, 0.f, 0.f};
    float4v o1 = {0.f, 0.f, 0.f, 0.f};
    o0 = mfma_bf16(ha, bq1[0], o0);
    o1 = mfma_bf16(ha, bq1[1], o1);
    if (rowX >= 0) {
        const short8v xa = *(const short8v*)(ap + rowX * 32 + k0);
        o0 = mfma_bf16(xa, bq2[0], o0);
        o1 = mfma_bf16(xa, bq2[1], o1);
    }

    // ---- store (C layout: row = kg*4+q, col = r / 16+r) ----
#pragma unroll
    for (int q = 0; q < 4; ++q) {
        const int nodeo = tile * 16 + kg * 4 + q;
        if (nodeo < N) {
            float* po = out + (size_t)nodeo * OUT_DIM + obase;
            po[r * ostride]        = o0[q];
            po[(16 + r) * ostride] = o1[q];
        }
    }
}

extern "C" void kernel_launch(void* const* d_in, const int* in_sizes, int n_in,
                              void* d_out, int out_size, void* d_ws, size_t ws_size,
                              hipStream_t stream) {
    const float* node0   = (const float*)d_in[0];
    const float* node1   = (const float*)d_in[1];
    const float* pos     = (const float*)d_in[2];
    const int*   senders = (const int*)d_in[3];
    const int*   recv    = (const int*)d_in[4];
    const float* Wpre0   = (const float*)d_in[5];
    const float* Wpre1   = (const float*)d_in[6];
    const float* Wpre2   = (const float*)d_in[7];
    const float* Wpost0  = (const float*)d_in[8];
    const float* Wpost1  = (const float*)d_in[9];
    const float* Wpost2  = (const float*)d_in[10];
    const float* Wsc0    = (const float*)d_in[11];
    const float* Wsc1    = (const float*)d_in[12];
    float* out = (float*)d_out;

    const int N = in_sizes[2] / 3;
    const int E = in_sizes[3];

    int* counts = (int*)d_ws;
    size_t adj_off = ((size_t)N * sizeof(int) + 15) & ~(size_t)15;
    float4* adj = (float4*)((char*)d_ws + adj_off);
    unsigned short* aggb = (unsigned short*)((char*)d_ws + adj_off + (size_t)N * MAXDEG * sizeof(float4));
    unsigned short* wt = aggb + (size_t)N * AGG_S;

    wprep_kernel<<<10, 256, 0, stream>>>(
        Wpre0, Wpre1, Wpre2, Wpost0, Wpost1, Wpost2, Wsc0, Wsc1, wt);
    zero_kernel<<<(N + 255) / 256, 256, 0, stream>>>(counts, N);
    scatter_sh_kernel<<<(E + 255) / 256, 256, 0, stream>>>(recv, senders, pos, E, counts, adj);
    edge_agg_kernel<<<(N + 1) / 2, 256, 0, stream>>>(node0, node1, counts, adj, aggb, N);

    const int ntiles = (N + 15) / 16;
    const int nwaves = ntiles * 9;
    node_mfma_kernel<<<(nwaves + 3) / 4, 256, 0, stream>>>(
        aggb, wt, out, N, ntiles);
}

// Round 13
// 44.140 us; speedup vs baseline: 1.1878x; 1.1878x over previous
//
#include <hip/hip_runtime.h>
#include <math.h>

#define C 32
#define OUT_DIM 288
#define MAXDEG 64
#define AGG_PAD 552   // 17*32 + 8 ushorts: 16B-aligned, 69 (odd) 16B-units -> conflict-free b128

typedef __attribute__((ext_vector_type(8))) short short8v;   // 8 bf16 (4 VGPRs)
typedef __attribute__((ext_vector_type(4))) float float4v;   // MFMA accumulator

__device__ __forceinline__ float4v mfma_bf16(short8v a, short8v b, float4v c) {
    return __builtin_amdgcn_mfma_f32_16x16x32_bf16(a, b, c, 0, 0, 0);
}

// f32 -> bf16 bits, round-to-nearest-even
__device__ __forceinline__ unsigned short f2b(float x) {
    unsigned int u = __float_as_uint(x);
    u = u + 0x7FFFu + ((u >> 16) & 1u);
    return (unsigned short)(u >> 16);
}

__device__ __forceinline__ float gelu_tanh(float x) {
    // jax.nn.gelu approximate=True
    float x3 = x * x * x;
    float t = tanhf(0.7978845608028654f * (x + 0.044715f * x3));
    return 0.5f * x * (1.0f + t);
}

// blocks 0-9: transpose+convert weights to bf16 WT[d][c]; blocks 10+: zero counts.
// wt blocks: 0:pre0_lo 1:pre0_hi 2:pre1_lo 3:pre1_hi 4:pre2 5:post0 6:post1
//            7:post2 8:sc0 9:sc1
__global__ void wprep_zero_kernel(const float* __restrict__ Wpre0,
                                  const float* __restrict__ Wpre1,
                                  const float* __restrict__ Wpre2,
                                  const float* __restrict__ Wpost0,
                                  const float* __restrict__ Wpost1,
                                  const float* __restrict__ Wpost2,
                                  const float* __restrict__ Wsc0,
                                  const float* __restrict__ Wsc1,
                                  unsigned short* __restrict__ wt,
                                  int* __restrict__ counts, int N) {
    const int b = blockIdx.x;
    if (b < 10) {
        const float* src;
        switch (b) {
            case 0: src = Wpre0;        break;
            case 1: src = Wpre0 + 1024; break;
            case 2: src = Wpre1;        break;
            case 3: src = Wpre1 + 1024; break;
            case 4: src = Wpre2;        break;
            case 5: src = Wpost0;       break;
            case 6: src = Wpost1;       break;
            case 7: src = Wpost2;       break;
            case 8: src = Wsc0;         break;
            default: src = Wsc1;        break;
        }
        unsigned short* dst = wt + b * 1024;
        for (int i = threadIdx.x; i < 1024; i += 256) {
            const int cc = i >> 5, dd = i & 31;
            dst[dd * 32 + cc] = f2b(src[cc * 32 + dd]);
        }
    } else {
        const int i = (b - 10) * 256 + threadIdx.x;
        if (i < N) counts[i] = 0;
    }
}

// Scatter into fixed-stride bins + spherical-harmonic precompute (rsqrt).
__global__ void scatter_sh_kernel(const int* __restrict__ recv,
                                  const int* __restrict__ senders,
                                  const float* __restrict__ pos, int E,
                                  int* __restrict__ counts, float4* __restrict__ adj) {
    int e = blockIdx.x * 256 + threadIdx.x;
    if (e < E) {
        const int r = recv[e];
        const int s = senders[e];
        const float rx = pos[r * 3 + 0] - pos[s * 3 + 0];
        const float ry = pos[r * 3 + 1] - pos[s * 3 + 1];
        const float rz = pos[r * 3 + 2] - pos[s * 3 + 2];
        const float d2 = rx * rx + ry * ry + rz * rz;
        const float f = 1.7320508075688772f * rsqrtf(fmaxf(d2, 1e-18f));
        const int p = atomicAdd(&counts[r], 1);
        if (p < MAXDEG)
            adj[(size_t)r * MAXDEG + p] = make_float4(rx * f, ry * f, rz * f, __int_as_float(s));
    }
}

// Fused: block = 1024 threads = 16 waves = one 16-node tile.
// Phase 1: wave w aggregates node tile*16+w (half split, 2-edge unroll, 4 chains),
//          writes 17 bf16 rows into LDS aggs[w].
// Phase 2 (after barrier): waves 0..8 run the 9 node-update MFMA tasks,
//          A-fragments straight from LDS, B-fragments from pre-transposed wt.
// MFMA layouts (16x16x32 bf16), HW-verified R11:
//   A: row=lane&15, k=(lane>>4)*8+j; B: col=lane&15, k=(lane>>4)*8+j;
//   C/D: col=lane&15, row=(lane>>4)*4+reg.
__global__ __launch_bounds__(1024) void fused_node_kernel(
    const float* __restrict__ node0, const float* __restrict__ node1,
    const int* __restrict__ counts, const float4* __restrict__ adj,
    const unsigned short* __restrict__ wt,
    float* __restrict__ out, int N)
{
    __shared__ unsigned short aggs[16 * AGG_PAD];
    __shared__ unsigned short tr[9][16][48];

    const int tid  = threadIdx.x;
    const int w    = tid >> 6;      // wave in block
    const int lane = tid & 63;
    const int half = lane >> 5;
    const int c    = lane & 31;
    const int tile = blockIdx.x;
    const int node = tile * 16 + w;
    const bool valid = (node < N);

    const float S2 = 0.70710678118654752f;   // 1/sqrt(2)
    const float S6 = 0.40824829046386302f;   // 1/sqrt(6)
    const float INV_SQRT3 = 0.57735026918962576f;
    const float INV_DEN = 1.0f / 16.0f;

    // ================= Phase 1: edge aggregation =================
    float ax0 = 0.f, atp0 = 0.f;
    float ax1x = 0.f, ax1y = 0.f, ax1z = 0.f;
    float at1x = 0.f, at1y = 0.f, at1z = 0.f;
    float a2v0 = 0.f, a2v1 = 0.f, a2v2 = 0.f, a2v3 = 0.f, a2v4 = 0.f;

#define EDGE_ACC(A, X0, U1)                                                 \
    {                                                                       \
        const float shx = (A).x, shy = (A).y, shz = (A).z;                  \
        ax0 += (X0);                                                        \
        atp0 += (U1).x * shx + (U1).y * shy + (U1).z * shz;                 \
        ax1x += (U1).x; ax1y += (U1).y; ax1z += (U1).z;                     \
        at1x += (X0) * shx; at1y += (X0) * shy; at1z += (X0) * shz;         \
        a2v0 += (U1).x * shy + (U1).y * shx;                                \
        a2v1 += (U1).y * shz + (U1).z * shy;                                \
        a2v2 += 2.f * (U1).z * shz - (U1).x * shx - (U1).y * shy;           \
        a2v3 += (U1).x * shz + (U1).z * shx;                                \
        a2v4 += (U1).x * shx - (U1).y * shy;                                \
    }

    if (valid) {
        const int deg = min(counts[node], MAXDEG);
        const int beg = node * MAXDEG;
        const int end = beg + deg;
        int k = beg + half;   // this half's edges: k, k+2, ...
        while (k + 2 < end) {
            const float4 A0 = adj[k];
            const float4 A1 = adj[k + 2];
            const int b0 = __float_as_int(A0.w) * C + c;
            const int b1 = __float_as_int(A1.w) * C + c;
            const float q0 = node0[b0];
            const float q1 = node0[b1];
            const float3 u0 = *(const float3*)(node1 + b0 * 3);
            const float3 u1 = *(const float3*)(node1 + b1 * 3);
            EDGE_ACC(A0, q0, u0);
            EDGE_ACC(A1, q1, u1);
            k += 4;
        }
        if (k < end) {
            const float4 A0 = adj[k];
            const int b0 = __float_as_int(A0.w) * C + c;
            const float q0 = node0[b0];
            const float3 u0 = *(const float3*)(node1 + b0 * 3);
            EDGE_ACC(A0, q0, u0);
        }
    }
#undef EDGE_ACC

    // combine halves (totals land in both halves)
    ax0  += __shfl_xor(ax0, 32, 64);
    atp0 += __shfl_xor(atp0, 32, 64);
    ax1x += __shfl_xor(ax1x, 32, 64);
    ax1y += __shfl_xor(ax1y, 32, 64);
    ax1z += __shfl_xor(ax1z, 32, 64);
    at1x += __shfl_xor(at1x, 32, 64);
    at1y += __shfl_xor(at1y, 32, 64);
    at1z += __shfl_xor(at1z, 32, 64);
    a2v0 += __shfl_xor(a2v0, 32, 64);
    a2v1 += __shfl_xor(a2v1, 32, 64);
    a2v2 += __shfl_xor(a2v2, 32, 64);
    a2v3 += __shfl_xor(a2v3, 32, 64);
    a2v4 += __shfl_xor(a2v4, 32, 64);

    {
        const int nfeat = valid ? node : 0;   // clamped loads; invalid rows only feed guarded stores
        const float x0n = node0[nfeat * C + c];
        const float3 xu = *(const float3*)(node1 + (nfeat * C + c) * 3);
        unsigned short* ag = aggs + w * AGG_PAD + c;
        const float SA = INV_DEN;
        const float SB = INV_DEN * INV_SQRT3;
        const float S2D = S2 * INV_DEN;
        const float S6D = S6 * INV_DEN;
        if (half == 0) {
            ag[0 * 32]  = f2b(ax0 * SA);
            ag[1 * 32]  = f2b(atp0 * SB);
            ag[2 * 32]  = f2b(ax1x * SA);
            ag[3 * 32]  = f2b(ax1y * SA);
            ag[4 * 32]  = f2b(ax1z * SA);
            ag[5 * 32]  = f2b(at1x * SA);
            ag[6 * 32]  = f2b(at1y * SA);
            ag[13 * 32] = f2b(x0n);
            ag[14 * 32] = f2b(xu.x);
        } else {
            ag[7 * 32]  = f2b(at1z * SA);
            ag[8 * 32]  = f2b(a2v0 * S2D);
            ag[9 * 32]  = f2b(a2v1 * S2D);
            ag[10 * 32] = f2b(a2v2 * S6D);
            ag[11 * 32] = f2b(a2v3 * S2D);
            ag[12 * 32] = f2b(a2v4 * S2D);
            ag[15 * 32] = f2b(xu.y);
            ag[16 * 32] = f2b(xu.z);
        }
    }
    __syncthreads();

    // ================= Phase 2: node-update MFMA (waves 0..8) =================
    if (w < 9) {
        const int t  = w;
        const int r  = lane & 15;
        const int kg = lane >> 4;
        const int k0 = kg * 8;

        const unsigned short *pb1, *pb2 = nullptr, *qb1, *qb2 = nullptr;
        int rowA1, rowA2 = -1, rowX = -1, obase, ostride;
        if (t == 0) {
            rowA1 = 0; rowA2 = 1; rowX = 13;
            pb1 = wt + 0 * 1024; pb2 = wt + 1 * 1024;
            qb1 = wt + 5 * 1024; qb2 = wt + 8 * 1024;
            obase = 0; ostride = 1;
        } else if (t <= 3) {
            const int i = t - 1;
            rowA1 = 2 + i; rowA2 = 5 + i; rowX = 14 + i;
            pb1 = wt + 2 * 1024; pb2 = wt + 3 * 1024;
            qb1 = wt + 6 * 1024; qb2 = wt + 9 * 1024;
            obase = 32 + i; ostride = 3;
        } else {
            const int m = t - 4;
            rowA1 = 8 + m;
            pb1 = wt + 4 * 1024; qb1 = wt + 7 * 1024;
            obase = 128 + m; ostride = 5;
        }

        const unsigned short* ap = aggs + r * AGG_PAD;

        // ---- pre-GEMM (B loads for pre only; post B loaded later to cap liveness) ----
        float4v acc0 = {0.f, 0.f, 0.f, 0.f};
        float4v acc1 = {0.f, 0.f, 0.f, 0.f};
        {
            const short8v a1 = *(const short8v*)(ap + rowA1 * 32 + k0);
            const short8v bp1a = *(const short8v*)(pb1 + (0 * 16 + r) * 32 + k0);
            const short8v bp1b = *(const short8v*)(pb1 + (1 * 16 + r) * 32 + k0);
            acc0 = mfma_bf16(a1, bp1a, acc0);
            acc1 = mfma_bf16(a1, bp1b, acc1);
        }
        if (rowA2 >= 0) {
            const short8v a2 = *(const short8v*)(ap + rowA2 * 32 + k0);
            const short8v bp2a = *(const short8v*)(pb2 + (0 * 16 + r) * 32 + k0);
            const short8v bp2b = *(const short8v*)(pb2 + (1 * 16 + r) * 32 + k0);
            acc0 = mfma_bf16(a2, bp2a, acc0);
            acc1 = mfma_bf16(a2, bp2b, acc1);
        }
        if (t == 0) {
#pragma unroll
            for (int q = 0; q < 4; ++q) {
                acc0[q] = gelu_tanh(acc0[q]);
                acc1[q] = gelu_tanh(acc1[q]);
            }
        }

        // ---- in-wave transpose: C layout -> A layout ----
#pragma unroll
        for (int q = 0; q < 4; ++q) {
            tr[w][kg * 4 + q][r]      = f2b(acc0[q]);
            tr[w][kg * 4 + q][16 + r] = f2b(acc1[q]);
        }
        asm volatile("s_waitcnt lgkmcnt(0)" ::: "memory");
        __builtin_amdgcn_sched_barrier(0);

        // ---- post-GEMM ----
        const short8v ha = *(const short8v*)&tr[w][r][k0];
        const short8v bq1a = *(const short8v*)(qb1 + (0 * 16 + r) * 32 + k0);
        const short8v bq1b = *(const short8v*)(qb1 + (1 * 16 + r) * 32 + k0);
        float4v o0 = {0.f, 0.f, 0.f, 0.f};
        float4v o1 = {0.f, 0.f, 0.f, 0.f};
        o0 = mfma_bf16(ha, bq1a, o0);
        o1 = mfma_bf16(ha, bq1b, o1);
        if (rowX >= 0) {
            const short8v xa = *(const short8v*)(ap + rowX * 32 + k0);
            const short8v bq2a = *(const short8v*)(qb2 + (0 * 16 + r) * 32 + k0);
            const short8v bq2b = *(const short8v*)(qb2 + (1 * 16 + r) * 32 + k0);
            o0 = mfma_bf16(xa, bq2a, o0);
            o1 = mfma_bf16(xa, bq2b, o1);
        }

        // ---- store (C layout: row = kg*4+q, col = r / 16+r) ----
#pragma unroll
        for (int q = 0; q < 4; ++q) {
            const int nodeo = tile * 16 + kg * 4 + q;
            if (nodeo < N) {
                float* po = out + (size_t)nodeo * OUT_DIM + obase;
                po[r * ostride]        = o0[q];
                po[(16 + r) * ostride] = o1[q];
            }
        }
    }
}

extern "C" void kernel_launch(void* const* d_in, const int* in_sizes, int n_in,
                              void* d_out, int out_size, void* d_ws, size_t ws_size,
                              hipStream_t stream) {
    const float* node0   = (const float*)d_in[0];
    const float* node1   = (const float*)d_in[1];
    const float* pos     = (const float*)d_in[2];
    const int*   senders = (const int*)d_in[3];
    const int*   recv    = (const int*)d_in[4];
    const float* Wpre0   = (const float*)d_in[5];
    const float* Wpre1   = (const float*)d_in[6];
    const float* Wpre2   = (const float*)d_in[7];
    const float* Wpost0  = (const float*)d_in[8];
    const float* Wpost1  = (const float*)d_in[9];
    const float* Wpost2  = (const float*)d_in[10];
    const float* Wsc0    = (const float*)d_in[11];
    const float* Wsc1    = (const float*)d_in[12];
    float* out = (float*)d_out;

    const int N = in_sizes[2] / 3;
    const int E = in_sizes[3];

    int* counts = (int*)d_ws;
    size_t adj_off = ((size_t)N * sizeof(int) + 15) & ~(size_t)15;
    float4* adj = (float4*)((char*)d_ws + adj_off);
    unsigned short* wt = (unsigned short*)((char*)d_ws + adj_off + (size_t)N * MAXDEG * sizeof(float4));

    const int zero_blocks = (N + 255) / 256;
    wprep_zero_kernel<<<10 + zero_blocks, 256, 0, stream>>>(
        Wpre0, Wpre1, Wpre2, Wpost0, Wpost1, Wpost2, Wsc0, Wsc1, wt, counts, N);
    scatter_sh_kernel<<<(E + 255) / 256, 256, 0, stream>>>(recv, senders, pos, E, counts, adj);

    const int ntiles = (N + 15) / 16;
    fused_node_kernel<<<ntiles, 1024, 0, stream>>>(
        node0, node1, counts, adj, wt, out, N);
}